// Round 4
// baseline (342.219 us; speedup 1.0000x reference)
//
#include <hip/hip_runtime.h>

#define B_ 32
#define E_ 48
#define M_ 96
#define D_ 256
#define H_ 8
#define DPH_ 32
#define MAXL_ 16   // data bound: 1 guaranteed + Binomial(48,1/48) extras (max ~9)
#define JT_ 16     // j-tile width in pairs kernel
#define RT_ 16     // rows per prep block, types 0/1
#define RT2_ 8     // rows per prep block, type 2 (2x work/row -> equal block cost)

// NOTE: parameter names must not collide with .x/.y/.z/.w member tokens
#define FMA4(A, s, v)                      \
    A[0] = fmaf((s), (v).x, A[0]);         \
    A[1] = fmaf((s), (v).y, A[1]);         \
    A[2] = fmaf((s), (v).z, A[2]);         \
    A[3] = fmaf((s), (v).w, A[3]);

// ---------------------------------------------------------------------------
// K0: bucket mentions by global entity id. lst stores LOCAL mention index.
__global__ __launch_bounds__(256) void build_lists_kernel(
    const int* __restrict__ info, int* __restrict__ cnt, int* __restrict__ lst) {
    int g = blockIdx.x * 256 + threadIdx.x;
    if (g >= B_ * M_) return;
    int e = info[g * 6];
    int pos = atomicAdd(&cnt[e], 1);
    if (pos < MAXL_) lst[e * MAXL_ + pos] = g % M_;
}

// ---------------------------------------------------------------------------
// K1: projections. Thread = (cg = tid&63 -> 4 consecutive output cols,
// rgp = tid>>6 -> row subgroup). W loads are coalesced float4 (1KB/wave inst,
// L1-dedup'd across the 4 waves); activation reads are same-address LDS
// broadcasts; stores are coalesced float4. Equal-cost blocks, type 2 first.
__global__ __launch_bounds__(256) void prep_kernel(
    const float* __restrict__ ent, const float* __restrict__ men,
    const float* __restrict__ sen, const int* __restrict__ info,
    const float* __restrict__ W1, const float* __restrict__ b1,
    const float* __restrict__ W2, const float* __restrict__ b2,
    float* __restrict__ qh, float* __restrict__ qt,
    float* __restrict__ k1, float* __restrict__ k2,
    float* __restrict__ u1, float* __restrict__ u2) {
    __shared__ float a[RT_][D_];   // 16 KB
    int bx = blockIdx.x;
    int tid = threadIdx.x;
    int type, rg, mha;
    if (bx < 768) { type = 2; rg = bx >> 1; mha = bx & 1; }
    else if (bx < 1152) { type = 1; rg = (bx - 768) >> 1; mha = bx & 1; }
    else { type = 0; rg = (bx - 1152) >> 1; mha = bx & 1; }

    const float* Wb = mha ? W2 : W1;
    const float* bb = mha ? b2 : b1;
    const float* W = Wb + (size_t)type * D_ * D_;
    int cg = tid & 63;    // col group: cols cg*4 .. cg*4+3
    int rgp = tid >> 6;   // row subgroup 0..3
    int c4 = cg * 4;

    if (type == 2) {
        // ---- type 2: v = men@Wv+b, then per-head u = v@Wo-slice ----------
        int rowbase = rg * RT2_;
#pragma unroll
        for (int t = 0; t < 2; ++t) {
            int idx = tid + t * 256;           // 0..511
            int r = idx >> 6, cc = (idx & 63) * 4;
            *(float4*)&a[r][cc] = *(const float4*)&men[(size_t)(rowbase + r) * D_ + cc];
        }
        __syncthreads();

        int r0 = rgp * 2;                       // 2 rows per thread
        float acc0[4], acc1[4];
        {
            float4 bv = *(const float4*)&bb[2 * D_ + c4];
            acc0[0] = bv.x; acc0[1] = bv.y; acc0[2] = bv.z; acc0[3] = bv.w;
            acc1[0] = bv.x; acc1[1] = bv.y; acc1[2] = bv.z; acc1[3] = bv.w;
        }
        for (int k = 0; k < D_; k += 4) {
            float4 w0 = *(const float4*)&W[(size_t)k * D_ + c4];
            float4 w1 = *(const float4*)&W[(size_t)(k + 1) * D_ + c4];
            float4 w2 = *(const float4*)&W[(size_t)(k + 2) * D_ + c4];
            float4 w3 = *(const float4*)&W[(size_t)(k + 3) * D_ + c4];
            float4 x0 = *(const float4*)&a[r0][k];
            float4 x1 = *(const float4*)&a[r0 + 1][k];
            FMA4(acc0, x0.x, w0); FMA4(acc0, x0.y, w1);
            FMA4(acc0, x0.z, w2); FMA4(acc0, x0.w, w3);
            FMA4(acc1, x1.x, w0); FMA4(acc1, x1.y, w1);
            FMA4(acc1, x1.z, w2); FMA4(acc1, x1.w, w3);
        }
        // park v in the unused upper half of a (rows 8..15, disjoint from the
        // input rows 0..7); barrier before reading so all writes land.
        *(float4*)&a[8 + r0][c4]     = make_float4(acc0[0], acc0[1], acc0[2], acc0[3]);
        *(float4*)&a[8 + r0 + 1][c4] = make_float4(acc1[0], acc1[1], acc1[2], acc1[3]);
        __syncthreads();

        const float* Wo = Wb + (size_t)3 * D_ * D_;
        float* u = mha ? u2 : u1;
        for (int h = 0; h < H_; ++h) {
#pragma unroll
            for (int i = 0; i < 4; ++i) { acc0[i] = 0.f; acc1[i] = 0.f; }
            for (int k = 0; k < DPH_; k += 4) {
                int kk = h * DPH_ + k;
                float4 w0 = *(const float4*)&Wo[(size_t)kk * D_ + c4];
                float4 w1 = *(const float4*)&Wo[(size_t)(kk + 1) * D_ + c4];
                float4 w2 = *(const float4*)&Wo[(size_t)(kk + 2) * D_ + c4];
                float4 w3 = *(const float4*)&Wo[(size_t)(kk + 3) * D_ + c4];
                float4 x0 = *(const float4*)&a[8 + r0][kk];
                float4 x1 = *(const float4*)&a[8 + r0 + 1][kk];
                FMA4(acc0, x0.x, w0); FMA4(acc0, x0.y, w1);
                FMA4(acc0, x0.z, w2); FMA4(acc0, x0.w, w3);
                FMA4(acc1, x1.x, w0); FMA4(acc1, x1.y, w1);
                FMA4(acc1, x1.z, w2); FMA4(acc1, x1.w, w3);
            }
            *(float4*)&u[((size_t)(rowbase + r0) * H_ + h) * D_ + c4] =
                make_float4(acc0[0], acc0[1], acc0[2], acc0[3]);
            *(float4*)&u[((size_t)(rowbase + r0 + 1) * H_ + h) * D_ + c4] =
                make_float4(acc1[0], acc1[1], acc1[2], acc1[3]);
        }
        return;
    }

    // ---- types 0/1: one GEMM pass over 16 rows, 4 rows per thread --------
    int rowbase = rg * RT_;
#pragma unroll
    for (int t = 0; t < 4; ++t) {
        int idx = tid + t * 256;               // 0..1023
        int r = idx >> 6, cc = (idx & 63) * 4;
        const float* src;
        if (type == 0) {
            src = &ent[(size_t)(rowbase + r) * D_ + cc];
        } else {
            int sid = info[(rowbase + r) * 6 + 4];
            src = &sen[(size_t)sid * D_ + cc];
        }
        *(float4*)&a[r][cc] = *(const float4*)src;
    }
    __syncthreads();

    int r0 = rgp * 4;                           // 4 rows per thread
    float acc0[4], acc1[4], acc2[4], acc3[4];
    {
        float4 bv = *(const float4*)&bb[type * D_ + c4];
        acc0[0] = bv.x; acc0[1] = bv.y; acc0[2] = bv.z; acc0[3] = bv.w;
#pragma unroll
        for (int i = 0; i < 4; ++i) { acc1[i] = acc0[i]; acc2[i] = acc0[i]; acc3[i] = acc0[i]; }
    }
    for (int k = 0; k < D_; k += 4) {
        float4 w0 = *(const float4*)&W[(size_t)k * D_ + c4];
        float4 w1 = *(const float4*)&W[(size_t)(k + 1) * D_ + c4];
        float4 w2 = *(const float4*)&W[(size_t)(k + 2) * D_ + c4];
        float4 w3 = *(const float4*)&W[(size_t)(k + 3) * D_ + c4];
        float4 x0 = *(const float4*)&a[r0][k];
        float4 x1 = *(const float4*)&a[r0 + 1][k];
        float4 x2 = *(const float4*)&a[r0 + 2][k];
        float4 x3 = *(const float4*)&a[r0 + 3][k];
        FMA4(acc0, x0.x, w0); FMA4(acc0, x0.y, w1); FMA4(acc0, x0.z, w2); FMA4(acc0, x0.w, w3);
        FMA4(acc1, x1.x, w0); FMA4(acc1, x1.y, w1); FMA4(acc1, x1.z, w2); FMA4(acc1, x1.w, w3);
        FMA4(acc2, x2.x, w0); FMA4(acc2, x2.y, w1); FMA4(acc2, x2.z, w2); FMA4(acc2, x2.w, w3);
        FMA4(acc3, x3.x, w0); FMA4(acc3, x3.y, w1); FMA4(acc3, x3.z, w2); FMA4(acc3, x3.w, w3);
    }

    float* o = (type == 0) ? (mha ? qt : qh) : (mha ? k2 : k1);
    *(float4*)&o[(size_t)(rowbase + r0) * D_ + c4]     = make_float4(acc0[0], acc0[1], acc0[2], acc0[3]);
    *(float4*)&o[(size_t)(rowbase + r0 + 1) * D_ + c4] = make_float4(acc1[0], acc1[1], acc1[2], acc1[3]);
    *(float4*)&o[(size_t)(rowbase + r0 + 2) * D_ + c4] = make_float4(acc2[0], acc2[1], acc2[2], acc2[3]);
    *(float4*)&o[(size_t)(rowbase + r0 + 3) * D_ + c4] = make_float4(acc3[0], acc3[1], acc3[2], acc3[3]);
}

// ---------------------------------------------------------------------------
// K2: scores. Block per (b, h, which). Writes ES[which][b][h][m][q] (q inner)
// so the pairs kernel's gathers over q are coalesced.
__global__ __launch_bounds__(256) void scores_kernel(
    const float* __restrict__ qh, const float* __restrict__ qt,
    const float* __restrict__ k1, const float* __restrict__ k2,
    float* __restrict__ ES) {
    int b = blockIdx.x, h = blockIdx.y, which = blockIdx.z;
    int tid = threadIdx.x;
    const float* q = (which ? qt : qh) + (size_t)b * E_ * D_ + h * DPH_;
    const float* kk = (which ? k2 : k1) + (size_t)b * M_ * D_ + h * DPH_;
    float* ESb = ES + (((size_t)which * B_ + b) * H_ + h) * (M_ * E_);

    __shared__ float qs[E_][DPH_ + 2];
    __shared__ float ks[M_][DPH_ + 2];
    __shared__ float Sb[E_][M_ + 2];
    __shared__ float mx[E_];

    for (int idx = tid; idx < E_ * DPH_; idx += 256) {
        int r = idx >> 5, c = idx & 31;
        qs[r][c] = q[(size_t)r * D_ + c];
    }
    for (int idx = tid; idx < M_ * DPH_; idx += 256) {
        int r = idx >> 5, c = idx & 31;
        ks[r][c] = kk[(size_t)r * D_ + c];
    }
    __syncthreads();
#pragma unroll
    for (int it = 0; it < 18; ++it) {            // 18*256 = 4608 = E*M
        int pair = tid + it * 256;
        int qi = pair / 96, m = pair % 96;
        float acc = 0.f;
#pragma unroll
        for (int c = 0; c < DPH_; c += 2) {
            float2 qv = *(const float2*)&qs[qi][c];
            float2 kv = *(const float2*)&ks[m][c];
            acc = fmaf(qv.x, kv.x, acc);
            acc = fmaf(qv.y, kv.y, acc);
        }
        Sb[qi][m] = acc * 0.17677669529663687f;  // 1/sqrt(32)
    }
    __syncthreads();
    if (tid < E_) {
        float mm = -1e30f;
        for (int m = 0; m < M_; ++m) mm = fmaxf(mm, Sb[tid][m]);
        mx[tid] = mm;
    }
    __syncthreads();
    for (int idx = tid; idx < E_ * M_; idx += 256) {
        int qi = idx % E_, m = idx / E_;
        ESb[m * E_ + qi] = __expf(Sb[qi][m] - mx[qi]);
    }
}

// ---------------------------------------------------------------------------
// K3: one block per (mask-entity me, doc b, which). 48 output rows in 3
// register-blocked tiles of JT_=16. ES gathers are coalesced float4 now.
__global__ __launch_bounds__(256) void pairs_kernel(
    const int* __restrict__ cnt_arr, const int* __restrict__ lst_arr,
    const float* __restrict__ ES,
    const float* __restrict__ u1, const float* __restrict__ u2,
    const float* __restrict__ ent,
    const float* __restrict__ bo1, const float* __restrict__ bo2,
    const float* __restrict__ ln1, const float* __restrict__ ln2,
    float* __restrict__ out) {
    int tid = threadIdx.x;
    int me = blockIdx.x;
    int b = blockIdx.y;
    int which = blockIdx.z;

    const float* ESb = ES + ((size_t)which * B_ + b) * (H_ * M_ * E_);
    const float* u = which ? u2 : u1;
    const float* bo = which ? bo2 : bo1;
    const float* ln = which ? ln2 : ln1;
    float* outb = out + ((size_t)which * B_ + b) * E_ * E_ * D_;

    __shared__ int lst[MAXL_];
    __shared__ float wj[MAXL_ * H_][JT_];    // 8 KB
    __shared__ float dinv_s[H_ * JT_];
    __shared__ float xbuf[JT_][D_ + 4];      // 16.6 KB
    __shared__ int cnt_s;

    if (tid == 0) cnt_s = min(cnt_arr[b * E_ + me], MAXL_);
    if (tid < MAXL_) lst[tid] = lst_arr[(b * E_ + me) * MAXL_ + tid];
    __syncthreads();
    int cnt = cnt_s;
    int K = cnt * H_;

    float bv = bo[tid];
    int wave = tid >> 6, lane = tid & 63;

    for (int j0 = 0; j0 < E_; j0 += JT_) {
        // gather exp-scores: coalesced float4 rows of 16 q's
        for (int idx = tid; idx < K * 4; idx += 256) {
            int k = idx >> 2, j4 = (idx & 3) * 4;
            int pos = k >> 3, h = k & 7;
            *(float4*)&wj[k][j4] =
                *(const float4*)&ESb[(size_t)(h * M_ + lst[pos]) * E_ + j0 + j4];
        }
        __syncthreads();
        if (tid < H_ * JT_) {
            int h = tid >> 4, j = tid & 15;
            float s = 0.f;
            for (int pos = 0; pos < cnt; ++pos) s += wj[pos * 8 + h][j];
            dinv_s[tid] = 1.0f / s;
        }
        __syncthreads();
        for (int idx = tid; idx < K * JT_; idx += 256) {
            int k = idx >> 4, j = idx & 15;
            wj[k][j] *= dinv_s[((k & 7) << 4) + j];
        }
        __syncthreads();

        // acc[j] += w[k][j] * u[k][tid]
        float acc[JT_];
#pragma unroll
        for (int j = 0; j < JT_; ++j) acc[j] = 0.f;
        for (int pos = 0; pos < cnt; ++pos) {
            const float* ub = u + (size_t)(b * M_ + lst[pos]) * (H_ * D_) + tid;
#pragma unroll
            for (int h = 0; h < H_; ++h) {
                float uval = ub[(size_t)h * D_];
                const float* wb = wj[pos * 8 + h];
                float4 w0 = *(const float4*)&wb[0];
                float4 w1 = *(const float4*)&wb[4];
                float4 w2 = *(const float4*)&wb[8];
                float4 w3 = *(const float4*)&wb[12];
                acc[0]  = fmaf(w0.x, uval, acc[0]);
                acc[1]  = fmaf(w0.y, uval, acc[1]);
                acc[2]  = fmaf(w0.z, uval, acc[2]);
                acc[3]  = fmaf(w0.w, uval, acc[3]);
                acc[4]  = fmaf(w1.x, uval, acc[4]);
                acc[5]  = fmaf(w1.y, uval, acc[5]);
                acc[6]  = fmaf(w1.z, uval, acc[6]);
                acc[7]  = fmaf(w1.w, uval, acc[7]);
                acc[8]  = fmaf(w2.x, uval, acc[8]);
                acc[9]  = fmaf(w2.y, uval, acc[9]);
                acc[10] = fmaf(w2.z, uval, acc[10]);
                acc[11] = fmaf(w2.w, uval, acc[11]);
                acc[12] = fmaf(w3.x, uval, acc[12]);
                acc[13] = fmaf(w3.y, uval, acc[13]);
                acc[14] = fmaf(w3.z, uval, acc[14]);
                acc[15] = fmaf(w3.w, uval, acc[15]);
            }
        }

        // stage x = residual + bias + ctx
#pragma unroll
        for (int j = 0; j < JT_; ++j) {
            float e = ent[(size_t)(b * E_ + j0 + j) * D_ + tid];
            xbuf[j][tid] = e + bv + acc[j];
        }
        __syncthreads();

        // LayerNorm: one row per wave, shuffle reduction, float4 store
        for (int jj = wave; jj < JT_; jj += 4) {
            float4 xv = *(const float4*)&xbuf[jj][lane * 4];
            float s = xv.x + xv.y + xv.z + xv.w;
            float sq = xv.x * xv.x + xv.y * xv.y + xv.z * xv.z + xv.w * xv.w;
#pragma unroll
            for (int off = 32; off > 0; off >>= 1) {
                s += __shfl_xor(s, off);
                sq += __shfl_xor(sq, off);
            }
            float mu = s * (1.0f / D_);
            float var = sq * (1.0f / D_) - mu * mu;
            float inv = rsqrtf(fmaxf(var, 0.f) + 1e-5f);
            float4 g = *(const float4*)&ln[lane * 4];
            float4 be = *(const float4*)&ln[D_ + lane * 4];
            float4 y;
            y.x = (xv.x - mu) * inv * g.x + be.x;
            y.y = (xv.y - mu) * inv * g.y + be.y;
            y.z = (xv.z - mu) * inv * g.z + be.z;
            y.w = (xv.w - mu) * inv * g.w + be.w;
            int o = j0 + jj;
            size_t orow = which ? ((size_t)o * E_ + me) : ((size_t)me * E_ + o);
            *(float4*)&outb[orow * D_ + lane * 4] = y;
        }
        __syncthreads();
    }
}

// ---------------------------------------------------------------------------
extern "C" void kernel_launch(void* const* d_in, const int* in_sizes, int n_in,
                              void* d_out, int out_size, void* d_ws, size_t ws_size,
                              hipStream_t stream) {
    const int* info = (const int*)d_in[0];
    const float* ent = (const float*)d_in[2];
    const float* men = (const float*)d_in[3];
    const float* sen = (const float*)d_in[4];
    const float* W1 = (const float*)d_in[5];
    const float* b1 = (const float*)d_in[6];
    const float* ln1 = (const float*)d_in[7];
    const float* W2 = (const float*)d_in[8];
    const float* b2 = (const float*)d_in[9];
    const float* ln2 = (const float*)d_in[10];
    float* out = (float*)d_out;

    float* ws = (float*)d_ws;
    size_t off = 0;
    float* qh = ws + off; off += (size_t)B_ * E_ * D_;
    float* qt = ws + off; off += (size_t)B_ * E_ * D_;
    float* k1 = ws + off; off += (size_t)B_ * M_ * D_;
    float* k2 = ws + off; off += (size_t)B_ * M_ * D_;
    float* u1 = ws + off; off += (size_t)B_ * M_ * H_ * D_;
    float* u2 = ws + off; off += (size_t)B_ * M_ * H_ * D_;
    float* ES = ws + off; off += (size_t)2 * B_ * H_ * M_ * E_;
    int* cnt = (int*)(ws + off); off += B_ * E_;
    int* lst = (int*)(ws + off); off += (size_t)B_ * E_ * MAXL_;

    hipMemsetAsync(cnt, 0, B_ * E_ * sizeof(int), stream);
    build_lists_kernel<<<(B_ * M_ + 255) / 256, 256, 0, stream>>>(info, cnt, lst);
    prep_kernel<<<1344, 256, 0, stream>>>(
        ent, men, sen, info, W1, b1, W2, b2, qh, qt, k1, k2, u1, u2);
    scores_kernel<<<dim3(B_, H_, 2), 256, 0, stream>>>(qh, qt, k1, k2, ES);
    pairs_kernel<<<dim3(E_, B_, 2), 256, 0, stream>>>(
        cnt, lst, ES, u1, u2, ent,
        b1 + 3 * D_, b2 + 3 * D_, ln1, ln2, out);
}

// Round 5
// 330.881 us; speedup vs baseline: 1.0343x; 1.0343x over previous
//
#include <hip/hip_runtime.h>

#define B_ 32
#define E_ 48
#define M_ 96
#define D_ 256
#define H_ 8
#define DPH_ 32
#define MAXL_ 16   // data bound: 1 guaranteed + Binomial(48,1/48) extras (max ~9)
#define JT_ 16     // j-tile width in pairs kernel
#define RT_ 16     // rows per prep block, types 0/1
#define RT2_ 8     // rows per prep block, type 2 (2x work/row -> equal block cost)

// NOTE: parameter names must not collide with .x/.y/.z/.w member tokens
#define FMA4(A, s, v)                      \
    A[0] = fmaf((s), (v).x, A[0]);         \
    A[1] = fmaf((s), (v).y, A[1]);         \
    A[2] = fmaf((s), (v).z, A[2]);         \
    A[3] = fmaf((s), (v).w, A[3]);

// ---------------------------------------------------------------------------
// K0: bucket mentions by global entity id. lst stores LOCAL mention index.
__global__ __launch_bounds__(256) void build_lists_kernel(
    const int* __restrict__ info, int* __restrict__ cnt, int* __restrict__ lst) {
    int g = blockIdx.x * 256 + threadIdx.x;
    if (g >= B_ * M_) return;
    int e = info[g * 6];
    int pos = atomicAdd(&cnt[e], 1);
    if (pos < MAXL_) lst[e * MAXL_ + pos] = g % M_;
}

// ---------------------------------------------------------------------------
// K1: projections. Thread = (cg = tid&63 -> 4 consecutive output cols,
// rgp = tid>>6 -> row subgroup). W loads coalesced float4; activation reads
// are same-address LDS broadcasts. NEW: depth-1 register double-buffer on W
// (issue k+4 group before FMAs of group k) to break load->use serialization
// (L2-latency-bound at ~2.8 waves/SIMD time-avg occupancy).
__global__ __launch_bounds__(256) void prep_kernel(
    const float* __restrict__ ent, const float* __restrict__ men,
    const float* __restrict__ sen, const int* __restrict__ info,
    const float* __restrict__ W1, const float* __restrict__ b1,
    const float* __restrict__ W2, const float* __restrict__ b2,
    float* __restrict__ qh, float* __restrict__ qt,
    float* __restrict__ k1, float* __restrict__ k2,
    float* __restrict__ u1, float* __restrict__ u2) {
    __shared__ float a[RT_][D_];   // 16 KB
    int bx = blockIdx.x;
    int tid = threadIdx.x;
    int type, rg, mha;
    if (bx < 768) { type = 2; rg = bx >> 1; mha = bx & 1; }
    else if (bx < 1152) { type = 1; rg = (bx - 768) >> 1; mha = bx & 1; }
    else { type = 0; rg = (bx - 1152) >> 1; mha = bx & 1; }

    const float* Wb = mha ? W2 : W1;
    const float* bb = mha ? b2 : b1;
    const float* W = Wb + (size_t)type * D_ * D_;
    int cg = tid & 63;    // col group: cols cg*4 .. cg*4+3
    int rgp = tid >> 6;   // row subgroup 0..3
    int c4 = cg * 4;

    if (type == 2) {
        // ---- type 2: v = men@Wv+b, then per-head u = v@Wo-slice ----------
        int rowbase = rg * RT2_;
#pragma unroll
        for (int t = 0; t < 2; ++t) {
            int idx = tid + t * 256;           // 0..511
            int r = idx >> 6, cc = (idx & 63) * 4;
            *(float4*)&a[r][cc] = *(const float4*)&men[(size_t)(rowbase + r) * D_ + cc];
        }
        __syncthreads();

        int r0 = rgp * 2;                       // 2 rows per thread
        float acc0[4], acc1[4];
        {
            float4 bv = *(const float4*)&bb[2 * D_ + c4];
            acc0[0] = bv.x; acc0[1] = bv.y; acc0[2] = bv.z; acc0[3] = bv.w;
            acc1[0] = bv.x; acc1[1] = bv.y; acc1[2] = bv.z; acc1[3] = bv.w;
        }
        float4 wa[4], wb[4];
#pragma unroll
        for (int j = 0; j < 4; ++j)
            wa[j] = *(const float4*)&W[(size_t)j * D_ + c4];
        for (int k = 0; k < D_; k += 8) {
#pragma unroll
            for (int j = 0; j < 4; ++j)
                wb[j] = *(const float4*)&W[(size_t)(k + 4 + j) * D_ + c4];
            {
                float4 x0 = *(const float4*)&a[r0][k];
                float4 x1 = *(const float4*)&a[r0 + 1][k];
                FMA4(acc0, x0.x, wa[0]); FMA4(acc0, x0.y, wa[1]);
                FMA4(acc0, x0.z, wa[2]); FMA4(acc0, x0.w, wa[3]);
                FMA4(acc1, x1.x, wa[0]); FMA4(acc1, x1.y, wa[1]);
                FMA4(acc1, x1.z, wa[2]); FMA4(acc1, x1.w, wa[3]);
            }
            if (k + 8 < D_) {
#pragma unroll
                for (int j = 0; j < 4; ++j)
                    wa[j] = *(const float4*)&W[(size_t)(k + 8 + j) * D_ + c4];
            }
            {
                float4 x0 = *(const float4*)&a[r0][k + 4];
                float4 x1 = *(const float4*)&a[r0 + 1][k + 4];
                FMA4(acc0, x0.x, wb[0]); FMA4(acc0, x0.y, wb[1]);
                FMA4(acc0, x0.z, wb[2]); FMA4(acc0, x0.w, wb[3]);
                FMA4(acc1, x1.x, wb[0]); FMA4(acc1, x1.y, wb[1]);
                FMA4(acc1, x1.z, wb[2]); FMA4(acc1, x1.w, wb[3]);
            }
        }
        // park v in the unused upper half of a (rows 8..15, disjoint from the
        // input rows 0..7); barrier before reading so all writes land.
        *(float4*)&a[8 + r0][c4]     = make_float4(acc0[0], acc0[1], acc0[2], acc0[3]);
        *(float4*)&a[8 + r0 + 1][c4] = make_float4(acc1[0], acc1[1], acc1[2], acc1[3]);
        __syncthreads();

        const float* Wo = Wb + (size_t)3 * D_ * D_;
        float* u = mha ? u2 : u1;
        // rolling prefetch across the whole 256 rows of Wo (flat kk), acc
        // resets/stores at head boundaries.
#pragma unroll
        for (int j = 0; j < 4; ++j)
            wa[j] = *(const float4*)&Wo[(size_t)j * D_ + c4];
        for (int h = 0; h < H_; ++h) {
#pragma unroll
            for (int i = 0; i < 4; ++i) { acc0[i] = 0.f; acc1[i] = 0.f; }
            for (int k = 0; k < DPH_; k += 8) {
                int kk = h * DPH_ + k;
#pragma unroll
                for (int j = 0; j < 4; ++j)
                    wb[j] = *(const float4*)&Wo[(size_t)(kk + 4 + j) * D_ + c4];
                {
                    float4 x0 = *(const float4*)&a[8 + r0][kk];
                    float4 x1 = *(const float4*)&a[8 + r0 + 1][kk];
                    FMA4(acc0, x0.x, wa[0]); FMA4(acc0, x0.y, wa[1]);
                    FMA4(acc0, x0.z, wa[2]); FMA4(acc0, x0.w, wa[3]);
                    FMA4(acc1, x1.x, wa[0]); FMA4(acc1, x1.y, wa[1]);
                    FMA4(acc1, x1.z, wa[2]); FMA4(acc1, x1.w, wa[3]);
                }
                if (kk + 8 < D_) {
#pragma unroll
                    for (int j = 0; j < 4; ++j)
                        wa[j] = *(const float4*)&Wo[(size_t)(kk + 8 + j) * D_ + c4];
                }
                {
                    float4 x0 = *(const float4*)&a[8 + r0][kk + 4];
                    float4 x1 = *(const float4*)&a[8 + r0 + 1][kk + 4];
                    FMA4(acc0, x0.x, wb[0]); FMA4(acc0, x0.y, wb[1]);
                    FMA4(acc0, x0.z, wb[2]); FMA4(acc0, x0.w, wb[3]);
                    FMA4(acc1, x1.x, wb[0]); FMA4(acc1, x1.y, wb[1]);
                    FMA4(acc1, x1.z, wb[2]); FMA4(acc1, x1.w, wb[3]);
                }
            }
            *(float4*)&u[((size_t)(rowbase + r0) * H_ + h) * D_ + c4] =
                make_float4(acc0[0], acc0[1], acc0[2], acc0[3]);
            *(float4*)&u[((size_t)(rowbase + r0 + 1) * H_ + h) * D_ + c4] =
                make_float4(acc1[0], acc1[1], acc1[2], acc1[3]);
        }
        return;
    }

    // ---- types 0/1: one GEMM pass over 16 rows, 4 rows per thread --------
    int rowbase = rg * RT_;
#pragma unroll
    for (int t = 0; t < 4; ++t) {
        int idx = tid + t * 256;               // 0..1023
        int r = idx >> 6, cc = (idx & 63) * 4;
        const float* src;
        if (type == 0) {
            src = &ent[(size_t)(rowbase + r) * D_ + cc];
        } else {
            int sid = info[(rowbase + r) * 6 + 4];
            src = &sen[(size_t)sid * D_ + cc];
        }
        *(float4*)&a[r][cc] = *(const float4*)src;
    }
    __syncthreads();

    int r0 = rgp * 4;                           // 4 rows per thread
    float acc0[4], acc1[4], acc2[4], acc3[4];
    {
        float4 bv = *(const float4*)&bb[type * D_ + c4];
        acc0[0] = bv.x; acc0[1] = bv.y; acc0[2] = bv.z; acc0[3] = bv.w;
#pragma unroll
        for (int i = 0; i < 4; ++i) { acc1[i] = acc0[i]; acc2[i] = acc0[i]; acc3[i] = acc0[i]; }
    }
    float4 wa[4], wb[4];
#pragma unroll
    for (int j = 0; j < 4; ++j)
        wa[j] = *(const float4*)&W[(size_t)j * D_ + c4];
    for (int k = 0; k < D_; k += 8) {
#pragma unroll
        for (int j = 0; j < 4; ++j)
            wb[j] = *(const float4*)&W[(size_t)(k + 4 + j) * D_ + c4];
        {
            float4 x0 = *(const float4*)&a[r0][k];
            float4 x1 = *(const float4*)&a[r0 + 1][k];
            float4 x2 = *(const float4*)&a[r0 + 2][k];
            float4 x3 = *(const float4*)&a[r0 + 3][k];
            FMA4(acc0, x0.x, wa[0]); FMA4(acc0, x0.y, wa[1]); FMA4(acc0, x0.z, wa[2]); FMA4(acc0, x0.w, wa[3]);
            FMA4(acc1, x1.x, wa[0]); FMA4(acc1, x1.y, wa[1]); FMA4(acc1, x1.z, wa[2]); FMA4(acc1, x1.w, wa[3]);
            FMA4(acc2, x2.x, wa[0]); FMA4(acc2, x2.y, wa[1]); FMA4(acc2, x2.z, wa[2]); FMA4(acc2, x2.w, wa[3]);
            FMA4(acc3, x3.x, wa[0]); FMA4(acc3, x3.y, wa[1]); FMA4(acc3, x3.z, wa[2]); FMA4(acc3, x3.w, wa[3]);
        }
        if (k + 8 < D_) {
#pragma unroll
            for (int j = 0; j < 4; ++j)
                wa[j] = *(const float4*)&W[(size_t)(k + 8 + j) * D_ + c4];
        }
        {
            float4 x0 = *(const float4*)&a[r0][k + 4];
            float4 x1 = *(const float4*)&a[r0 + 1][k + 4];
            float4 x2 = *(const float4*)&a[r0 + 2][k + 4];
            float4 x3 = *(const float4*)&a[r0 + 3][k + 4];
            FMA4(acc0, x0.x, wb[0]); FMA4(acc0, x0.y, wb[1]); FMA4(acc0, x0.z, wb[2]); FMA4(acc0, x0.w, wb[3]);
            FMA4(acc1, x1.x, wb[0]); FMA4(acc1, x1.y, wb[1]); FMA4(acc1, x1.z, wb[2]); FMA4(acc1, x1.w, wb[3]);
            FMA4(acc2, x2.x, wb[0]); FMA4(acc2, x2.y, wb[1]); FMA4(acc2, x2.z, wb[2]); FMA4(acc2, x2.w, wb[3]);
            FMA4(acc3, x3.x, wb[0]); FMA4(acc3, x3.y, wb[1]); FMA4(acc3, x3.z, wb[2]); FMA4(acc3, x3.w, wb[3]);
        }
    }

    float* o = (type == 0) ? (mha ? qt : qh) : (mha ? k2 : k1);
    *(float4*)&o[(size_t)(rowbase + r0) * D_ + c4]     = make_float4(acc0[0], acc0[1], acc0[2], acc0[3]);
    *(float4*)&o[(size_t)(rowbase + r0 + 1) * D_ + c4] = make_float4(acc1[0], acc1[1], acc1[2], acc1[3]);
    *(float4*)&o[(size_t)(rowbase + r0 + 2) * D_ + c4] = make_float4(acc2[0], acc2[1], acc2[2], acc2[3]);
    *(float4*)&o[(size_t)(rowbase + r0 + 3) * D_ + c4] = make_float4(acc3[0], acc3[1], acc3[2], acc3[3]);
}

// ---------------------------------------------------------------------------
// K2: scores. Block per (b, h, which). Writes ES[which][b][h][m][q] (q inner)
// so the pairs kernel's gathers over q are coalesced.
__global__ __launch_bounds__(256) void scores_kernel(
    const float* __restrict__ qh, const float* __restrict__ qt,
    const float* __restrict__ k1, const float* __restrict__ k2,
    float* __restrict__ ES) {
    int b = blockIdx.x, h = blockIdx.y, which = blockIdx.z;
    int tid = threadIdx.x;
    const float* q = (which ? qt : qh) + (size_t)b * E_ * D_ + h * DPH_;
    const float* kk = (which ? k2 : k1) + (size_t)b * M_ * D_ + h * DPH_;
    float* ESb = ES + (((size_t)which * B_ + b) * H_ + h) * (M_ * E_);

    __shared__ float qs[E_][DPH_ + 2];
    __shared__ float ks[M_][DPH_ + 2];
    __shared__ float Sb[E_][M_ + 2];
    __shared__ float mx[E_];

    for (int idx = tid; idx < E_ * DPH_; idx += 256) {
        int r = idx >> 5, c = idx & 31;
        qs[r][c] = q[(size_t)r * D_ + c];
    }
    for (int idx = tid; idx < M_ * DPH_; idx += 256) {
        int r = idx >> 5, c = idx & 31;
        ks[r][c] = kk[(size_t)r * D_ + c];
    }
    __syncthreads();
#pragma unroll
    for (int it = 0; it < 18; ++it) {            // 18*256 = 4608 = E*M
        int pair = tid + it * 256;
        int qi = pair / 96, m = pair % 96;
        float acc = 0.f;
#pragma unroll
        for (int c = 0; c < DPH_; c += 2) {
            float2 qv = *(const float2*)&qs[qi][c];
            float2 kv = *(const float2*)&ks[m][c];
            acc = fmaf(qv.x, kv.x, acc);
            acc = fmaf(qv.y, kv.y, acc);
        }
        Sb[qi][m] = acc * 0.17677669529663687f;  // 1/sqrt(32)
    }
    __syncthreads();
    if (tid < E_) {
        float mm = -1e30f;
        for (int m = 0; m < M_; ++m) mm = fmaxf(mm, Sb[tid][m]);
        mx[tid] = mm;
    }
    __syncthreads();
    for (int idx = tid; idx < E_ * M_; idx += 256) {
        int qi = idx % E_, m = idx / E_;
        ESb[m * E_ + qi] = __expf(Sb[qi][m] - mx[qi]);
    }
}

// ---------------------------------------------------------------------------
// K3: one block per (mask-entity me, doc b, which). 48 output rows in 3
// register-blocked tiles of JT_=16. ES gathers are coalesced float4 now.
__global__ __launch_bounds__(256) void pairs_kernel(
    const int* __restrict__ cnt_arr, const int* __restrict__ lst_arr,
    const float* __restrict__ ES,
    const float* __restrict__ u1, const float* __restrict__ u2,
    const float* __restrict__ ent,
    const float* __restrict__ bo1, const float* __restrict__ bo2,
    const float* __restrict__ ln1, const float* __restrict__ ln2,
    float* __restrict__ out) {
    int tid = threadIdx.x;
    int me = blockIdx.x;
    int b = blockIdx.y;
    int which = blockIdx.z;

    const float* ESb = ES + ((size_t)which * B_ + b) * (H_ * M_ * E_);
    const float* u = which ? u2 : u1;
    const float* bo = which ? bo2 : bo1;
    const float* ln = which ? ln2 : ln1;
    float* outb = out + ((size_t)which * B_ + b) * E_ * E_ * D_;

    __shared__ int lst[MAXL_];
    __shared__ float wj[MAXL_ * H_][JT_];    // 8 KB
    __shared__ float dinv_s[H_ * JT_];
    __shared__ float xbuf[JT_][D_ + 4];      // 16.6 KB
    __shared__ int cnt_s;

    if (tid == 0) cnt_s = min(cnt_arr[b * E_ + me], MAXL_);
    if (tid < MAXL_) lst[tid] = lst_arr[(b * E_ + me) * MAXL_ + tid];
    __syncthreads();
    int cnt = cnt_s;
    int K = cnt * H_;

    float bv = bo[tid];
    int wave = tid >> 6, lane = tid & 63;

    for (int j0 = 0; j0 < E_; j0 += JT_) {
        // gather exp-scores: coalesced float4 rows of 16 q's
        for (int idx = tid; idx < K * 4; idx += 256) {
            int k = idx >> 2, j4 = (idx & 3) * 4;
            int pos = k >> 3, h = k & 7;
            *(float4*)&wj[k][j4] =
                *(const float4*)&ESb[(size_t)(h * M_ + lst[pos]) * E_ + j0 + j4];
        }
        __syncthreads();
        if (tid < H_ * JT_) {
            int h = tid >> 4, j = tid & 15;
            float s = 0.f;
            for (int pos = 0; pos < cnt; ++pos) s += wj[pos * 8 + h][j];
            dinv_s[tid] = 1.0f / s;
        }
        __syncthreads();
        for (int idx = tid; idx < K * JT_; idx += 256) {
            int k = idx >> 4, j = idx & 15;
            wj[k][j] *= dinv_s[((k & 7) << 4) + j];
        }
        __syncthreads();

        // acc[j] += w[k][j] * u[k][tid]
        float acc[JT_];
#pragma unroll
        for (int j = 0; j < JT_; ++j) acc[j] = 0.f;
        for (int pos = 0; pos < cnt; ++pos) {
            const float* ub = u + (size_t)(b * M_ + lst[pos]) * (H_ * D_) + tid;
#pragma unroll
            for (int h = 0; h < H_; ++h) {
                float uval = ub[(size_t)h * D_];
                const float* wb = wj[pos * 8 + h];
                float4 w0 = *(const float4*)&wb[0];
                float4 w1 = *(const float4*)&wb[4];
                float4 w2 = *(const float4*)&wb[8];
                float4 w3 = *(const float4*)&wb[12];
                acc[0]  = fmaf(w0.x, uval, acc[0]);
                acc[1]  = fmaf(w0.y, uval, acc[1]);
                acc[2]  = fmaf(w0.z, uval, acc[2]);
                acc[3]  = fmaf(w0.w, uval, acc[3]);
                acc[4]  = fmaf(w1.x, uval, acc[4]);
                acc[5]  = fmaf(w1.y, uval, acc[5]);
                acc[6]  = fmaf(w1.z, uval, acc[6]);
                acc[7]  = fmaf(w1.w, uval, acc[7]);
                acc[8]  = fmaf(w2.x, uval, acc[8]);
                acc[9]  = fmaf(w2.y, uval, acc[9]);
                acc[10] = fmaf(w2.z, uval, acc[10]);
                acc[11] = fmaf(w2.w, uval, acc[11]);
                acc[12] = fmaf(w3.x, uval, acc[12]);
                acc[13] = fmaf(w3.y, uval, acc[13]);
                acc[14] = fmaf(w3.z, uval, acc[14]);
                acc[15] = fmaf(w3.w, uval, acc[15]);
            }
        }

        // stage x = residual + bias + ctx
#pragma unroll
        for (int j = 0; j < JT_; ++j) {
            float e = ent[(size_t)(b * E_ + j0 + j) * D_ + tid];
            xbuf[j][tid] = e + bv + acc[j];
        }
        __syncthreads();

        // LayerNorm: one row per wave, shuffle reduction, float4 store
        for (int jj = wave; jj < JT_; jj += 4) {
            float4 xv = *(const float4*)&xbuf[jj][lane * 4];
            float s = xv.x + xv.y + xv.z + xv.w;
            float sq = xv.x * xv.x + xv.y * xv.y + xv.z * xv.z + xv.w * xv.w;
#pragma unroll
            for (int off = 32; off > 0; off >>= 1) {
                s += __shfl_xor(s, off);
                sq += __shfl_xor(sq, off);
            }
            float mu = s * (1.0f / D_);
            float var = sq * (1.0f / D_) - mu * mu;
            float inv = rsqrtf(fmaxf(var, 0.f) + 1e-5f);
            float4 g = *(const float4*)&ln[lane * 4];
            float4 be = *(const float4*)&ln[D_ + lane * 4];
            float4 y;
            y.x = (xv.x - mu) * inv * g.x + be.x;
            y.y = (xv.y - mu) * inv * g.y + be.y;
            y.z = (xv.z - mu) * inv * g.z + be.z;
            y.w = (xv.w - mu) * inv * g.w + be.w;
            int o = j0 + jj;
            size_t orow = which ? ((size_t)o * E_ + me) : ((size_t)me * E_ + o);
            *(float4*)&outb[orow * D_ + lane * 4] = y;
        }
        __syncthreads();
    }
}

// ---------------------------------------------------------------------------
extern "C" void kernel_launch(void* const* d_in, const int* in_sizes, int n_in,
                              void* d_out, int out_size, void* d_ws, size_t ws_size,
                              hipStream_t stream) {
    const int* info = (const int*)d_in[0];
    const float* ent = (const float*)d_in[2];
    const float* men = (const float*)d_in[3];
    const float* sen = (const float*)d_in[4];
    const float* W1 = (const float*)d_in[5];
    const float* b1 = (const float*)d_in[6];
    const float* ln1 = (const float*)d_in[7];
    const float* W2 = (const float*)d_in[8];
    const float* b2 = (const float*)d_in[9];
    const float* ln2 = (const float*)d_in[10];
    float* out = (float*)d_out;

    float* ws = (float*)d_ws;
    size_t off = 0;
    float* qh = ws + off; off += (size_t)B_ * E_ * D_;
    float* qt = ws + off; off += (size_t)B_ * E_ * D_;
    float* k1 = ws + off; off += (size_t)B_ * M_ * D_;
    float* k2 = ws + off; off += (size_t)B_ * M_ * D_;
    float* u1 = ws + off; off += (size_t)B_ * M_ * H_ * D_;
    float* u2 = ws + off; off += (size_t)B_ * M_ * H_ * D_;
    float* ES = ws + off; off += (size_t)2 * B_ * H_ * M_ * E_;
    int* cnt = (int*)(ws + off); off += B_ * E_;
    int* lst = (int*)(ws + off); off += (size_t)B_ * E_ * MAXL_;

    hipMemsetAsync(cnt, 0, B_ * E_ * sizeof(int), stream);
    build_lists_kernel<<<(B_ * M_ + 255) / 256, 256, 0, stream>>>(info, cnt, lst);
    prep_kernel<<<1344, 256, 0, stream>>>(
        ent, men, sen, info, W1, b1, W2, b2, qh, qt, k1, k2, u1, u2);
    scores_kernel<<<dim3(B_, H_, 2), 256, 0, stream>>>(qh, qt, k1, k2, ES);
    pairs_kernel<<<dim3(E_, B_, 2), 256, 0, stream>>>(
        cnt, lst, ES, u1, u2, ent,
        b1 + 3 * D_, b2 + 3 * D_, ln1, ln2, out);
}